// Round 1
// baseline (342.689 us; speedup 1.0000x reference)
//
#include <hip/hip_runtime.h>
#include <math.h>

#define N_NODES 50000
#define N_EDGES 800000
#define D 64

// ---------------- workspace layout (byte offsets, 1KiB aligned) ----------------
// counts   : int[N_NODES]      @ 0         (200000 -> 200704)
// offsets  : int[N_NODES+1]    @ 200704    (200004 -> 200704)
// pos      : int[N_NODES]      @ 401408    (200000 -> 200704)
// partials : int[64]           @ 602112    (256    -> 1024)
// csr_src  : int[N_EDGES]      @ 603136    (3200000)
// x1       : float[N_NODES*D]  @ 3803136   (12800000)
// x2       : float[N_NODES*D]  @ 16603136  (12800000)
// total ~= 29.4 MB

__global__ void zero_counts_kernel(int* __restrict__ counts) {
    int i = blockIdx.x * blockDim.x + threadIdx.x;
    if (i < N_NODES) counts[i] = 0;
}

__global__ void hist_kernel(const int* __restrict__ dst, int* __restrict__ counts) {
    int i = blockIdx.x * blockDim.x + threadIdx.x;
    if (i < N_EDGES) atomicAdd(&counts[dst[i]], 1);
}

// chunk = 1024 counts per block; 49 blocks
__global__ void chunk_sum_kernel(const int* __restrict__ counts, int* __restrict__ partials) {
    __shared__ int sdata[256];
    int base = blockIdx.x * 1024;
    int tid = threadIdx.x;
    int sum = 0;
    for (int i = tid; i < 1024; i += 256) {
        int idx = base + i;
        sum += (idx < N_NODES) ? counts[idx] : 0;
    }
    sdata[tid] = sum;
    __syncthreads();
    for (int s = 128; s > 0; s >>= 1) {
        if (tid < s) sdata[tid] += sdata[tid + s];
        __syncthreads();
    }
    if (tid == 0) partials[blockIdx.x] = sdata[0];
}

// single wave: exclusive scan of nchunks (<=64) partials in place
__global__ void partial_scan_kernel(int* __restrict__ partials, int nchunks) {
    int lane = threadIdx.x;
    int v = (lane < nchunks) ? partials[lane] : 0;
    int orig = v;
    for (int off = 1; off < 64; off <<= 1) {
        int t = __shfl_up(v, off);
        if (lane >= off) v += t;
    }
    if (lane < nchunks) partials[lane] = v - orig;  // exclusive
}

// 49 blocks x 256 threads; each block scans its 1024-count chunk, adds base,
// writes exclusive offsets (and a second copy 'pos' used as scatter cursors)
__global__ void chunk_scan_kernel(const int* __restrict__ counts,
                                  const int* __restrict__ partials,
                                  int* __restrict__ offsets,
                                  int* __restrict__ pos) {
    __shared__ int sdata[256];
    int base = blockIdx.x * 1024;
    int tid = threadIdx.x;
    int v[4];
    int s = 0;
    for (int j = 0; j < 4; ++j) {
        int idx = base + tid * 4 + j;
        v[j] = (idx < N_NODES) ? counts[idx] : 0;
        s += v[j];
    }
    sdata[tid] = s;
    __syncthreads();
    // Hillis-Steele inclusive scan over 256 per-thread sums
    for (int off = 1; off < 256; off <<= 1) {
        int t = (tid >= off) ? sdata[tid - off] : 0;
        __syncthreads();
        sdata[tid] += t;
        __syncthreads();
    }
    int excl = sdata[tid] - s + partials[blockIdx.x];
    for (int j = 0; j < 4; ++j) {
        int idx = base + tid * 4 + j;
        if (idx < N_NODES) {
            offsets[idx] = excl;
            pos[idx] = excl;
        }
        excl += v[j];
        if (idx == N_NODES - 1) offsets[N_NODES] = excl;  // total == N_EDGES
    }
}

__global__ void scatter_kernel(const int* __restrict__ src, const int* __restrict__ dst,
                               int* __restrict__ pos, int* __restrict__ csr_src) {
    int i = blockIdx.x * blockDim.x + threadIdx.x;
    if (i < N_EDGES) {
        int slot = atomicAdd(&pos[dst[i]], 1);
        csr_src[slot] = src[i];
    }
}

// Fused: mean-aggregate incoming neighbors (pull via CSR) + x@W_self + h@W_neigh + b, relu.
// One wave per node; lane = output feature. W matrices staged in LDS.
__global__ __launch_bounds__(256) void sage_layer_kernel(
    const float* __restrict__ x_in,
    const int* __restrict__ offsets,
    const int* __restrict__ csr_src,
    const float* __restrict__ W_self, const float* __restrict__ W_neigh,
    const float* __restrict__ bias,
    float* __restrict__ x_out) {
    __shared__ float Ws[D * D];
    __shared__ float Wn[D * D];
    __shared__ float bs[D];
    __shared__ float arow[4][D];
    __shared__ float hrow[4][D];

    int tid = threadIdx.x;
    for (int i = tid; i < D * D; i += 256) {
        Ws[i] = W_self[i];
        Wn[i] = W_neigh[i];
    }
    if (tid < D) bs[tid] = bias[tid];

    int wave = tid >> 6;
    int lane = tid & 63;
    int node = blockIdx.x * 4 + wave;  // grid is exactly N_NODES/4 -> always valid

    int e0 = offsets[node];
    int e1 = offsets[node + 1];
    float acc = 0.f;
    int e = e0;
    for (; e + 4 <= e1; e += 4) {
        int s0 = csr_src[e + 0];
        int s1 = csr_src[e + 1];
        int s2 = csr_src[e + 2];
        int s3 = csr_src[e + 3];
        acc += x_in[s0 * D + lane];
        acc += x_in[s1 * D + lane];
        acc += x_in[s2 * D + lane];
        acc += x_in[s3 * D + lane];
    }
    for (; e < e1; ++e) acc += x_in[csr_src[e] * D + lane];

    float deg = (float)(e1 - e0);
    float hn = acc / fmaxf(deg, 1.0f);
    float a = x_in[node * D + lane];

    arow[wave][lane] = a;
    hrow[wave][lane] = hn;
    __syncthreads();  // all waves reach this (no early return; grid covers nodes exactly)

    float o = bs[lane];
#pragma unroll 16
    for (int k = 0; k < D; ++k) {
        o += arow[wave][k] * Ws[k * D + lane] + hrow[wave][k] * Wn[k * D + lane];
    }
    x_out[node * D + lane] = fmaxf(o, 0.f);
}

// 16 lanes per edge: float4 per lane, shfl_xor reduce within the 16-group.
__global__ __launch_bounds__(256) void edge_dot_kernel(
    const float* __restrict__ x, const int* __restrict__ src,
    const int* __restrict__ dst, float* __restrict__ out) {
    int t = blockIdx.x * 256 + threadIdx.x;
    int e = t >> 4;
    int sub = t & 15;
    if (e >= N_EDGES) return;
    int s = src[e], d = dst[e];
    const float4* xs = (const float4*)(x + (size_t)s * D);
    const float4* xd = (const float4*)(x + (size_t)d * D);
    float4 a = xs[sub];
    float4 b = xd[sub];
    float p = a.x * b.x + a.y * b.y + a.z * b.z + a.w * b.w;
    p += __shfl_xor(p, 1);
    p += __shfl_xor(p, 2);
    p += __shfl_xor(p, 4);
    p += __shfl_xor(p, 8);
    if (sub == 0) {
        float s1 = 1.f / (1.f + __expf(-p));
        float s2 = 1.f / (1.f + __expf(-s1));
        out[e] = s2;
    }
}

extern "C" void kernel_launch(void* const* d_in, const int* in_sizes, int n_in,
                              void* d_out, int out_size, void* d_ws, size_t ws_size,
                              hipStream_t stream) {
    const float* feats = (const float*)d_in[0];
    const int* src = (const int*)d_in[1];
    const int* dst = (const int*)d_in[2];
    const float* Ws1 = (const float*)d_in[3];
    const float* Wn1 = (const float*)d_in[4];
    const float* b1 = (const float*)d_in[5];
    const float* Ws2 = (const float*)d_in[6];
    const float* Wn2 = (const float*)d_in[7];
    const float* b2 = (const float*)d_in[8];
    float* out = (float*)d_out;

    char* ws = (char*)d_ws;
    int* counts   = (int*)(ws + 0);
    int* offsets  = (int*)(ws + 200704);
    int* pos      = (int*)(ws + 401408);
    int* partials = (int*)(ws + 602112);
    int* csr_src  = (int*)(ws + 603136);
    float* x1     = (float*)(ws + 3803136);
    float* x2     = (float*)(ws + 16603136);

    zero_counts_kernel<<<(N_NODES + 255) / 256, 256, 0, stream>>>(counts);
    hist_kernel<<<(N_EDGES + 255) / 256, 256, 0, stream>>>(dst, counts);
    chunk_sum_kernel<<<49, 256, 0, stream>>>(counts, partials);
    partial_scan_kernel<<<1, 64, 0, stream>>>(partials, 49);
    chunk_scan_kernel<<<49, 256, 0, stream>>>(counts, partials, offsets, pos);
    scatter_kernel<<<(N_EDGES + 255) / 256, 256, 0, stream>>>(src, dst, pos, csr_src);

    sage_layer_kernel<<<N_NODES / 4, 256, 0, stream>>>(feats, offsets, csr_src, Ws1, Wn1, b1, x1);
    sage_layer_kernel<<<N_NODES / 4, 256, 0, stream>>>(x1, offsets, csr_src, Ws2, Wn2, b2, x2);

    edge_dot_kernel<<<(N_EDGES * 16 + 255) / 256, 256, 0, stream>>>(x2, src, dst, out);
}

// Round 2
// 263.659 us; speedup vs baseline: 1.2997x; 1.2997x over previous
//
#include <hip/hip_runtime.h>
#include <math.h>

#define N_NODES 50000
#define N_EDGES 800000
#define D 64

// ---------------- workspace layout (byte offsets, 1KiB aligned) ----------------
// counts   : int[N_NODES]      @ 0
// offsets  : int[N_NODES+1]    @ 200704
// pos      : int[N_NODES]      @ 401408
// partials : int[64]           @ 602112
// csr_src  : int[N_EDGES]      @ 603136
// x1       : float[N_NODES*D]  @ 3803136
// x2       : float[N_NODES*D]  @ 16603136

__global__ void zero_counts_kernel(int* __restrict__ counts) {
    int i = blockIdx.x * blockDim.x + threadIdx.x;
    if (i < N_NODES) counts[i] = 0;
}

__global__ void hist_kernel(const int* __restrict__ dst, int* __restrict__ counts) {
    int i = blockIdx.x * blockDim.x + threadIdx.x;
    if (i < N_EDGES) atomicAdd(&counts[dst[i]], 1);
}

__global__ void chunk_sum_kernel(const int* __restrict__ counts, int* __restrict__ partials) {
    __shared__ int sdata[256];
    int base = blockIdx.x * 1024;
    int tid = threadIdx.x;
    int sum = 0;
    for (int i = tid; i < 1024; i += 256) {
        int idx = base + i;
        sum += (idx < N_NODES) ? counts[idx] : 0;
    }
    sdata[tid] = sum;
    __syncthreads();
    for (int s = 128; s > 0; s >>= 1) {
        if (tid < s) sdata[tid] += sdata[tid + s];
        __syncthreads();
    }
    if (tid == 0) partials[blockIdx.x] = sdata[0];
}

__global__ void partial_scan_kernel(int* __restrict__ partials, int nchunks) {
    int lane = threadIdx.x;
    int v = (lane < nchunks) ? partials[lane] : 0;
    int orig = v;
    for (int off = 1; off < 64; off <<= 1) {
        int t = __shfl_up(v, off);
        if (lane >= off) v += t;
    }
    if (lane < nchunks) partials[lane] = v - orig;  // exclusive
}

__global__ void chunk_scan_kernel(const int* __restrict__ counts,
                                  const int* __restrict__ partials,
                                  int* __restrict__ offsets,
                                  int* __restrict__ pos) {
    __shared__ int sdata[256];
    int base = blockIdx.x * 1024;
    int tid = threadIdx.x;
    int v[4];
    int s = 0;
    for (int j = 0; j < 4; ++j) {
        int idx = base + tid * 4 + j;
        v[j] = (idx < N_NODES) ? counts[idx] : 0;
        s += v[j];
    }
    sdata[tid] = s;
    __syncthreads();
    for (int off = 1; off < 256; off <<= 1) {
        int t = (tid >= off) ? sdata[tid - off] : 0;
        __syncthreads();
        sdata[tid] += t;
        __syncthreads();
    }
    int excl = sdata[tid] - s + partials[blockIdx.x];
    for (int j = 0; j < 4; ++j) {
        int idx = base + tid * 4 + j;
        if (idx < N_NODES) {
            offsets[idx] = excl;
            pos[idx] = excl;
        }
        excl += v[j];
        if (idx == N_NODES - 1) offsets[N_NODES] = excl;
    }
}

__global__ void scatter_kernel(const int* __restrict__ src, const int* __restrict__ dst,
                               int* __restrict__ pos, int* __restrict__ csr_src) {
    int i = blockIdx.x * blockDim.x + threadIdx.x;
    if (i < N_EDGES) {
        int slot = atomicAdd(&pos[dst[i]], 1);
        csr_src[slot] = src[i];
    }
}

// Fused SAGE layer, v2.
// Block = 256 threads = 4 waves; each wave owns 16 nodes (4 groups x 16 lanes,
// group g handles nodes m*4+g for m=0..3). Gather: one global_load_dwordx4
// per 4 rows, unroll 4 -> 16 rows in flight per wave. GEMM: W staged as
// float4 rows in LDS (b128 reads, shared across 16 nodes via registers);
// h rows in LDS with stride-17-float4 padding (conflict-free group-broadcast
// reads); self rows 'a' read from global (L1-resident block region).
// LDS = 16K(Ws)+16K(Wn)+17.4K(h) = 50176 B -> 3 blocks/CU.
__global__ __launch_bounds__(256) void sage_layer_kernel(
    const float* __restrict__ x_in,
    const int* __restrict__ offsets,
    const int* __restrict__ csr_src,
    const float* __restrict__ W_self, const float* __restrict__ W_neigh,
    const float* __restrict__ bias,
    float* __restrict__ x_out) {
    __shared__ float4 Ws4[D * 16];        // [k][sub]
    __shared__ float4 Wn4[D * 16];        // [k][sub]
    __shared__ float4 hL[4][16 * 17];     // [wave][node_local*17 + kk]

    const int tid = threadIdx.x;
    const int w = tid >> 6;
    const int lane = tid & 63;
    const int g = lane >> 4;
    const int sub = lane & 15;

    // stage weights as float4
    {
        const float4* ws_g = (const float4*)W_self;
        const float4* wn_g = (const float4*)W_neigh;
        for (int i = tid; i < D * 16; i += 256) {
            Ws4[i] = ws_g[i];
            Wn4[i] = wn_g[i];
        }
    }
    __syncthreads();

    const int base = blockIdx.x * 64;
    const float4* x4 = (const float4*)x_in;

    // ---- gather phase: group g aggregates nodes base + w*16 + m*4 + g ----
#pragma unroll
    for (int m = 0; m < 4; ++m) {
        int node = base + w * 16 + m * 4 + g;
        int e0 = 0, e1 = 0;
        if (node < N_NODES) {
            e0 = offsets[node];
            e1 = offsets[node + 1];
        }
        float4 acc = make_float4(0.f, 0.f, 0.f, 0.f);
        int e = e0;
        for (; e + 4 <= e1; e += 4) {
            int s0 = csr_src[e + 0];
            int s1 = csr_src[e + 1];
            int s2 = csr_src[e + 2];
            int s3 = csr_src[e + 3];
            float4 r0 = x4[s0 * 16 + sub];
            float4 r1 = x4[s1 * 16 + sub];
            float4 r2 = x4[s2 * 16 + sub];
            float4 r3 = x4[s3 * 16 + sub];
            acc.x += r0.x + r1.x + r2.x + r3.x;
            acc.y += r0.y + r1.y + r2.y + r3.y;
            acc.z += r0.z + r1.z + r2.z + r3.z;
            acc.w += r0.w + r1.w + r2.w + r3.w;
        }
        for (; e < e1; ++e) {
            float4 r = x4[csr_src[e] * 16 + sub];
            acc.x += r.x; acc.y += r.y; acc.z += r.z; acc.w += r.w;
        }
        float inv = 1.0f / fmaxf((float)(e1 - e0), 1.0f);
        acc.x *= inv; acc.y *= inv; acc.z *= inv; acc.w *= inv;
        hL[w][(m * 4 + g) * 17 + sub] = acc;
    }
    // hL written and read by the same wave -> wave-coherent via lgkmcnt (no barrier)

    // ---- GEMM phase: out[node] = relu(a @ Ws + h @ Wn + b) ----
    const float4 b4 = ((const float4*)bias)[sub];
    float4 accs0 = b4, accs1 = b4, accs2 = b4, accs3 = b4;

    // clamped row pointers for self rows (valid-address even for tail nodes)
    int n0 = base + w * 16 + 0 * 4 + g; if (n0 > N_NODES - 1) n0 = N_NODES - 1;
    int n1 = base + w * 16 + 1 * 4 + g; if (n1 > N_NODES - 1) n1 = N_NODES - 1;
    int n2 = base + w * 16 + 2 * 4 + g; if (n2 > N_NODES - 1) n2 = N_NODES - 1;
    int n3 = base + w * 16 + 3 * 4 + g; if (n3 > N_NODES - 1) n3 = N_NODES - 1;
    const float4* arow0 = x4 + n0 * 16;
    const float4* arow1 = x4 + n1 * 16;
    const float4* arow2 = x4 + n2 * 16;
    const float4* arow3 = x4 + n3 * 16;
    const float4* hrow0 = &hL[w][(0 * 4 + g) * 17];
    const float4* hrow1 = &hL[w][(1 * 4 + g) * 17];
    const float4* hrow2 = &hL[w][(2 * 4 + g) * 17];
    const float4* hrow3 = &hL[w][(3 * 4 + g) * 17];

    for (int kk = 0; kk < 16; ++kk) {
        float4 ws0 = Ws4[(kk * 4 + 0) * 16 + sub];
        float4 ws1 = Ws4[(kk * 4 + 1) * 16 + sub];
        float4 ws2 = Ws4[(kk * 4 + 2) * 16 + sub];
        float4 ws3 = Ws4[(kk * 4 + 3) * 16 + sub];
        float4 wn0 = Wn4[(kk * 4 + 0) * 16 + sub];
        float4 wn1 = Wn4[(kk * 4 + 1) * 16 + sub];
        float4 wn2 = Wn4[(kk * 4 + 2) * 16 + sub];
        float4 wn3 = Wn4[(kk * 4 + 3) * 16 + sub];

#define SAGE_FMA(ACC, A4, H4)                                                   \
        {                                                                       \
            float4 a4 = (A4); float4 h4 = (H4);                                 \
            ACC.x += a4.x * ws0.x + a4.y * ws1.x + a4.z * ws2.x + a4.w * ws3.x  \
                   + h4.x * wn0.x + h4.y * wn1.x + h4.z * wn2.x + h4.w * wn3.x; \
            ACC.y += a4.x * ws0.y + a4.y * ws1.y + a4.z * ws2.y + a4.w * ws3.y  \
                   + h4.x * wn0.y + h4.y * wn1.y + h4.z * wn2.y + h4.w * wn3.y; \
            ACC.z += a4.x * ws0.z + a4.y * ws1.z + a4.z * ws2.z + a4.w * ws3.z  \
                   + h4.x * wn0.z + h4.y * wn1.z + h4.z * wn2.z + h4.w * wn3.z; \
            ACC.w += a4.x * ws0.w + a4.y * ws1.w + a4.z * ws2.w + a4.w * ws3.w  \
                   + h4.x * wn0.w + h4.y * wn1.w + h4.z * wn2.w + h4.w * wn3.w; \
        }
        SAGE_FMA(accs0, arow0[kk], hrow0[kk]);
        SAGE_FMA(accs1, arow1[kk], hrow1[kk]);
        SAGE_FMA(accs2, arow2[kk], hrow2[kk]);
        SAGE_FMA(accs3, arow3[kk], hrow3[kk]);
#undef SAGE_FMA
    }

    float4* out4 = (float4*)x_out;
#define SAGE_STORE(M, ACC)                                                      \
    {                                                                           \
        int node = base + w * 16 + (M) * 4 + g;                                 \
        if (node < N_NODES) {                                                   \
            float4 r;                                                           \
            r.x = fmaxf(ACC.x, 0.f); r.y = fmaxf(ACC.y, 0.f);                   \
            r.z = fmaxf(ACC.z, 0.f); r.w = fmaxf(ACC.w, 0.f);                   \
            out4[node * 16 + sub] = r;                                          \
        }                                                                       \
    }
    SAGE_STORE(0, accs0);
    SAGE_STORE(1, accs1);
    SAGE_STORE(2, accs2);
    SAGE_STORE(3, accs3);
#undef SAGE_STORE
}

// 16 lanes per edge: float4 per lane, shfl_xor reduce within the 16-group.
__global__ __launch_bounds__(256) void edge_dot_kernel(
    const float* __restrict__ x, const int* __restrict__ src,
    const int* __restrict__ dst, float* __restrict__ out) {
    int t = blockIdx.x * 256 + threadIdx.x;
    int e = t >> 4;
    int sub = t & 15;
    if (e >= N_EDGES) return;
    int s = src[e], d = dst[e];
    const float4* xs = (const float4*)(x + (size_t)s * D);
    const float4* xd = (const float4*)(x + (size_t)d * D);
    float4 a = xs[sub];
    float4 b = xd[sub];
    float p = a.x * b.x + a.y * b.y + a.z * b.z + a.w * b.w;
    p += __shfl_xor(p, 1);
    p += __shfl_xor(p, 2);
    p += __shfl_xor(p, 4);
    p += __shfl_xor(p, 8);
    if (sub == 0) {
        float s1 = 1.f / (1.f + __expf(-p));
        float s2 = 1.f / (1.f + __expf(-s1));
        out[e] = s2;
    }
}

extern "C" void kernel_launch(void* const* d_in, const int* in_sizes, int n_in,
                              void* d_out, int out_size, void* d_ws, size_t ws_size,
                              hipStream_t stream) {
    const float* feats = (const float*)d_in[0];
    const int* src = (const int*)d_in[1];
    const int* dst = (const int*)d_in[2];
    const float* Ws1 = (const float*)d_in[3];
    const float* Wn1 = (const float*)d_in[4];
    const float* b1 = (const float*)d_in[5];
    const float* Ws2 = (const float*)d_in[6];
    const float* Wn2 = (const float*)d_in[7];
    const float* b2 = (const float*)d_in[8];
    float* out = (float*)d_out;

    char* ws = (char*)d_ws;
    int* counts   = (int*)(ws + 0);
    int* offsets  = (int*)(ws + 200704);
    int* pos      = (int*)(ws + 401408);
    int* partials = (int*)(ws + 602112);
    int* csr_src  = (int*)(ws + 603136);
    float* x1     = (float*)(ws + 3803136);
    float* x2     = (float*)(ws + 16603136);

    zero_counts_kernel<<<(N_NODES + 255) / 256, 256, 0, stream>>>(counts);
    hist_kernel<<<(N_EDGES + 255) / 256, 256, 0, stream>>>(dst, counts);
    chunk_sum_kernel<<<49, 256, 0, stream>>>(counts, partials);
    partial_scan_kernel<<<1, 64, 0, stream>>>(partials, 49);
    chunk_scan_kernel<<<49, 256, 0, stream>>>(counts, partials, offsets, pos);
    scatter_kernel<<<(N_EDGES + 255) / 256, 256, 0, stream>>>(src, dst, pos, csr_src);

    const int sage_grid = (N_NODES + 63) / 64;  // 782
    sage_layer_kernel<<<sage_grid, 256, 0, stream>>>(feats, offsets, csr_src, Ws1, Wn1, b1, x1);
    sage_layer_kernel<<<sage_grid, 256, 0, stream>>>(x1, offsets, csr_src, Ws2, Wn2, b2, x2);

    edge_dot_kernel<<<(N_EDGES * 16 + 255) / 256, 256, 0, stream>>>(x2, src, dst, out);
}